// Round 11
// baseline (322.909 us; speedup 1.0000x reference)
//
#include <hip/hip_runtime.h>

#define THRF 0.05f

// ---------------------------------------------------------------------------
// Fused pre-pass: latency encode (one-hot mask per pixel) + weight transposes.
//  w1T[k*32+oc]          = W1[oc*9+k]
//  w2T[kk*1024+ic*32+oc] = W2[oc*288+ic*9+kk]
//  WdT[f*64+o]           = Wd[o*1568+f]
// ---------------------------------------------------------------------------
__global__ void k_pre(const float* __restrict__ x, const float* __restrict__ W1,
                      const float* __restrict__ W2, const float* __restrict__ Wd,
                      unsigned* __restrict__ mIn, float* __restrict__ w1T,
                      float* __restrict__ w2T, float* __restrict__ WdT) {
  int i = blockIdx.x * blockDim.x + threadIdx.x;
  if (i >= 100352) return;
  float xv = x[i];
  float st = fminf(19.0f * (1.0f - xv), 19.0f * 0.95f);
  int t = (int)rintf(st);
  t = t < 0 ? 0 : (t > 19 ? 19 : t);
  mIn[i] = (xv >= THRF) ? (1u << t) : 0u;
  { int o = i / 1568, f = i % 1568; WdT[f * 64 + o] = Wd[i]; }
  if (i < 9216) {
    int oc = i / 288, k = i % 288, ic = k / 9, kk = k % 9;
    w2T[kk * 1024 + ic * 32 + oc] = W2[i];
  }
  if (i < 288) { int oc = i / 9, k = i % 9; w1T[k * 32 + oc] = W1[i]; }
}

// ---------------------------------------------------------------------------
// Stage 1: conv1(3x3 SAME, 1->32) + LIF + maxpool, lane-parallel over t.
// (unchanged from passing rounds 6-10)
// ---------------------------------------------------------------------------
__global__ __launch_bounds__(128) void k_stage1M(const unsigned* __restrict__ mIn,
                                                 const float* __restrict__ w1T,
                                                 unsigned* __restrict__ z1p) {
  __shared__ float xp[2][20 * 66];
  int lane = threadIdx.x & 63;
  int wid  = threadIdx.x >> 6;
  int gw   = blockIdx.x * 2 + wid;     // wave index
  int pA = 2 * gw, pB = 2 * gw + 1;    // pre-pool pixel = b*784 + y*28 + x
  int bA = pA / 784, rA = pA % 784, yA = rA / 28, xA = rA % 28;
  int bB = pB / 784, rB = pB % 784, yB = rB / 28, xB = rB % 28;
  int tl = lane & 31, hiB = lane >> 5;

  unsigned mA[9], mB[9];
  for (int ky = 0; ky < 3; ++ky) {
    for (int kx = 0; kx < 3; ++kx) {
      int k = ky * 3 + kx;
      int ya = yA - 1 + ky, xa = xA - 1 + kx;
      int yb = yB - 1 + ky, xb = xB - 1 + kx;
      mA[k] = (ya >= 0 && ya < 28 && xa >= 0 && xa < 28) ? mIn[bA * 784 + ya * 28 + xa] : 0u;
      mB[k] = (yb >= 0 && yb < 28 && xb >= 0 && xb < 28) ? mIn[bB * 784 + yb * 28 + xb] : 0u;
    }
  }

  float acc[32];
#pragma unroll
  for (int o = 0; o < 32; ++o) acc[o] = 0.0f;

  for (int k = 0; k < 9; ++k) {
    unsigned long long m64 = ((unsigned long long)mB[k] << 32) | (unsigned long long)mA[k];
    float bitf = (float)((m64 >> lane) & 1ull);
    const float* wrow = w1T + k * 32;
#pragma unroll
    for (int oc = 0; oc < 32; ++oc)
      acc[oc] = fmaf(wrow[oc], bitf, acc[oc]);
  }

  if (tl < 20) {
#pragma unroll
    for (int oc = 0; oc < 32; ++oc)
      xp[wid][tl * 66 + hiB * 32 + oc] = acc[oc];
  }
  __syncthreads();

  float v = 0.0f;
  int   r = 0;
  unsigned zm = 0u;
#pragma unroll
  for (int t = 0; t < 20; ++t) {
    float c = xp[wid][t * 66 + lane];
    v += c;
    bool z = (v > THRF) && (r == 0);
    if (z) { v -= THRF; r = 3; } else if (r > 0) --r;
    if (z) zm |= 1u << t;
  }
  int p = hiB ? pB : pA;
  int b = p / 784, rr = p % 784, y = rr / 28, x = rr % 28;
  atomicOr(&z1p[((b * 14 + (y >> 1)) * 14 + (x >> 1)) * 32 + tl], zm);
}

// ---------------------------------------------------------------------------
// Stage 2: conv2 + LIF + maxpool — round-9 shape (3 px/wave, 4 waves/block)
// + block-cooperative DOUBLE-BUFFERED LDS WEIGHT STAGING.
// All 4 waves consume the same (ky,kx,ic) weight sequence, so per cell the
// block stages the next cell's 4 KB of weights into LDS (one float4 per
// thread) overlapped with compute; one __syncthreads per cell. Inner-loop
// weight reads are wave-uniform LDS broadcasts -> VMEM off the critical
// path. Masks stay on the vector path (wide per-lane loads, prefetched one
// cell ahead; round-8 lesson: never SMEM). Per ic: 3 readlane -> 2 cndmask
// -> bfe+cvt -> 32 fmac. Accumulation per (neuron,t): ascending (ky,kx,ic),
// ic innermost — identical to all passing rounds; bit=0 adds +0.0 exactly.
// Epilogue: per-wave [20][33] LDS buffer, 3 wave-internal sub-passes
// (same-wave LDS ordering needs no barrier), LIF in-register, pool via
// deterministic atomicOr into pre-zeroed z2p.
// ---------------------------------------------------------------------------
__global__ __launch_bounds__(256) void k_stage2G(const unsigned* __restrict__ z1p,
                                                 const float* __restrict__ wT2,
                                                 const unsigned* __restrict__ zbuf,
                                                 unsigned* __restrict__ z2p) {
  __shared__ float4 wbuf4[2][256];       // 2 x 4 KB cell weights
  __shared__ float  xp[4][20 * 33];      // per-wave epilogue transpose
  int tid  = threadIdx.x;
  int lane = tid & 63;
  int wid  = tid >> 6;
  int gw   = blockIdx.x * 4 + wid;       // wave index
  int q0 = 3 * gw;                       // pixels: b*196 + y*14 + x

  int bb[3], yy[3], xx[3];
  bool vq[3];
#pragma unroll
  for (int j = 0; j < 3; ++j) {
    int q = q0 + j;
    vq[j] = q < 25088;
    int qs = vq[j] ? q : 0;
    bb[j] = qs / 196; int rr = qs % 196; yy[j] = rr / 14; xx[j] = rr % 14;
  }

  int  li = lane & 31;
  bool lo = lane < 32;
  int  p  = lane / 20;                   // 0..3 (p==3 idle in epilogue)
  int  tl = lane - p * 20;

  float acc[32];
#pragma unroll
  for (int o = 0; o < 32; ++o) acc[o] = 0.0f;

  auto cptr = [&](int cell, const unsigned*& c0, const unsigned*& c1,
                  const unsigned*& c2) {
    int ky = cell / 3, kx = cell % 3;
    const unsigned* cp[3];
#pragma unroll
    for (int j = 0; j < 3; ++j) {
      int y = yy[j] - 1 + ky, x = xx[j] - 1 + kx;
      bool ok = vq[j] && y >= 0 && y < 14 && x >= 0 && x < 14;
      cp[j] = ok ? (z1p + ((bb[j] * 14 + y) * 14 + x) * 32) : zbuf;
    }
    c0 = cp[0]; c1 = cp[1]; c2 = cp[2];
  };

  // stage cell 0 weights + cell 0 masks
  wbuf4[0][tid] = *(const float4*)(wT2 + tid * 4);
  const unsigned *c0, *c1, *c2;
  cptr(0, c0, c1, c2);
  unsigned va = (lo ? c0 : c1)[li];
  unsigned vb = c2[li];
  __syncthreads();

  for (int cell = 0; cell < 9; ++cell) {
    int cur = cell & 1;
    unsigned va_n = 0u, vb_n = 0u;
    if (cell + 1 < 9) {
      // prefetch next cell: weights -> LDS (other buffer), masks -> regs
      wbuf4[cur ^ 1][tid] = *(const float4*)(wT2 + (cell + 1) * 1024 + tid * 4);
      const unsigned *n0, *n1, *n2;
      cptr(cell + 1, n0, n1, n2);
      va_n = (lo ? n0 : n1)[li];
      vb_n = n2[li];
    }
    const float* wc = (const float*)wbuf4[cur];
#pragma unroll 4
    for (int ic = 0; ic < 32; ++ic) {
      unsigned s0 = (unsigned)__builtin_amdgcn_readlane((int)va, ic);
      unsigned s1 = (unsigned)__builtin_amdgcn_readlane((int)va, 32 + ic);
      unsigned s2 = (unsigned)__builtin_amdgcn_readlane((int)vb, ic);
      unsigned mm = (p == 0) ? s0 : ((p == 1) ? s1 : s2);
      float bitf = (float)((mm >> tl) & 1u);
      const float* wrow = wc + ic * 32;
#pragma unroll
      for (int oc = 0; oc < 32; ++oc)
        acc[oc] = fmaf(wrow[oc], bitf, acc[oc]);
    }
    va = va_n; vb = vb_n;
    __syncthreads();   // cur buffer free for overwrite next iteration
  }

  // per-wave epilogue: 3 sub-passes (pixel j), wave-internal LDS ordering
  float* xw = xp[wid];
#pragma unroll
  for (int j = 0; j < 3; ++j) {
    if (p == j) {
#pragma unroll
      for (int oc = 0; oc < 32; ++oc) xw[tl * 33 + oc] = acc[oc];
    }
    int oc = lane & 31;
    float v = 0.0f;
    int   r = 0;
    unsigned zm = 0u;
#pragma unroll
    for (int t = 0; t < 20; ++t) {
      float c = xw[t * 33 + oc];
      v += c;
      bool z = (v > THRF) && (r == 0);
      if (z) { v -= THRF; r = 3; } else if (r > 0) --r;
      if (z) zm |= 1u << t;
    }
    if (lane < 32 && vq[j])
      atomicOr(&z2p[bb[j] * 1568 + oc * 49 + (yy[j] >> 1) * 7 + (xx[j] >> 1)], zm);
  }
}

// ---------------------------------------------------------------------------
// Stage 3: dense currents + OUTPUT LIF fused (unchanged from round 10).
// 3 outputs/wave, 4 waves/block, A/B double-buffered mask+weight prefetch.
// ---------------------------------------------------------------------------
__global__ __launch_bounds__(256) void k_denseF(const unsigned* __restrict__ z2p,
                                                const float* __restrict__ WdT,
                                                float* __restrict__ out) {
  int lane = threadIdx.x & 63;
  int wid  = threadIdx.x >> 6;
  int gw   = blockIdx.x * 4 + wid;     // b*22 + og
  if (gw >= 128 * 22) return;
  int b  = gw / 22, og = gw % 22;
  int p  = lane / 20;                  // 0..3 (p==3 idle)
  int t  = lane - p * 20;
  int o  = og * 3 + p;
  bool live = (p < 3) && (o < 64);
  int osafe = live ? o : 63;
  const unsigned* zb = z2p + b * 1568;

  unsigned mA[16], mB[16];
  float    wA[16], wB[16];
#pragma unroll
  for (int u = 0; u < 16; ++u) { mA[u] = zb[u]; wA[u] = WdT[u * 64 + osafe]; }

  float acc = 0.0f;
  for (int f0 = 0; f0 < 1568; f0 += 32) {   // 1568 = 32*49
#pragma unroll
    for (int u = 0; u < 16; ++u) {
      int fn = f0 + 16 + u;
      mB[u] = zb[fn]; wB[u] = WdT[fn * 64 + osafe];
    }
#pragma unroll
    for (int u = 0; u < 16; ++u) {
      float bitf = (float)((mA[u] >> t) & 1u);
      acc = fmaf(wA[u], bitf, acc);
    }
    if (f0 + 32 < 1568) {
#pragma unroll
      for (int u = 0; u < 16; ++u) {
        int fn = f0 + 32 + u;
        mA[u] = zb[fn]; wA[u] = WdT[fn * 64 + osafe];
      }
    }
#pragma unroll
    for (int u = 0; u < 16; ++u) {
      float bitf = (float)((mB[u] >> t) & 1u);
      acc = fmaf(wB[u], bitf, acc);
    }
  }

  float v = 0.0f;
  int   r = 0;
  unsigned zm = 0u;
#pragma unroll
  for (int tt = 0; tt < 20; ++tt) {
    float c = __shfl(acc, p * 20 + tt, 64);  // p==3 lanes: garbage, discarded
    v += c;
    bool z = (v > THRF) && (r == 0);
    if (z) { v -= THRF; r = 3; } else if (r > 0) --r;
    if (z) zm |= 1u << tt;
  }
  if (live) out[(b * 20 + t) * 64 + o] = ((zm >> t) & 1u) ? 1.0f : 0.0f;
}

extern "C" void kernel_launch(void* const* d_in, const int* in_sizes, int n_in,
                              void* d_out, int out_size, void* d_ws, size_t ws_size,
                              hipStream_t stream) {
  const float* x  = (const float*)d_in[0];  // [128,1,28,28]
  const float* W1 = (const float*)d_in[1];  // [32,1,3,3]
  const float* W2 = (const float*)d_in[2];  // [32,32,3,3]
  const float* Wd = (const float*)d_in[3];  // [64,1568]
  float* out = (float*)d_out;               // [128,20,64]

  char* ws = (char*)d_ws;
  unsigned* mIn  = (unsigned*)ws;                      // 401408 B (dead after stage1)
  unsigned* z1p  = (unsigned*)(ws + 655360);           // 3211264 B (zeroed; atomicOr)
  unsigned* z2p  = (unsigned*)(ws + 3866624);          // 802816 B (zeroed; atomicOr)
  unsigned* zbuf = (unsigned*)(ws + 4669440);          // 128 B zeros
  float*    w1T  = (float*)(ws + 4669568);             // 1152 B
  float*    w2T  = (float*)(ws + 4670720);             // 36864 B
  float*    WdT  = (float*)(ws + 4707584);             // 401408 B

  k_pre<<<dim3(392), dim3(256), 0, stream>>>(x, W1, W2, Wd, mIn, w1T, w2T, WdT);
  hipMemsetAsync(ws + 655360, 0, 3211264 + 802816 + 128, stream);  // z1p+z2p+zbuf
  k_stage1M<<<dim3(25088), dim3(128), 0, stream>>>(mIn, w1T, z1p);
  k_stage2G<<<dim3(2091), dim3(256), 0, stream>>>(z1p, w2T, zbuf, z2p);
  k_denseF<<<dim3(704), dim3(256), 0, stream>>>(z2p, WdT, out);
}

// Round 12
// 287.550 us; speedup vs baseline: 1.1230x; 1.1230x over previous
//
#include <hip/hip_runtime.h>

#define THRF 0.05f

// ---------------------------------------------------------------------------
// Fused pre-pass: latency encode (one-hot mask per pixel) + weight transposes.
//  w1T[k*32+oc]          = W1[oc*9+k]
//  w2T[kk*1024+ic*32+oc] = W2[oc*288+ic*9+kk]
//  WdT[f*64+o]           = Wd[o*1568+f]
// ---------------------------------------------------------------------------
__global__ void k_pre(const float* __restrict__ x, const float* __restrict__ W1,
                      const float* __restrict__ W2, const float* __restrict__ Wd,
                      unsigned* __restrict__ mIn, float* __restrict__ w1T,
                      float* __restrict__ w2T, float* __restrict__ WdT) {
  int i = blockIdx.x * blockDim.x + threadIdx.x;
  if (i >= 100352) return;
  float xv = x[i];
  float st = fminf(19.0f * (1.0f - xv), 19.0f * 0.95f);
  int t = (int)rintf(st);
  t = t < 0 ? 0 : (t > 19 ? 19 : t);
  mIn[i] = (xv >= THRF) ? (1u << t) : 0u;
  { int o = i / 1568, f = i % 1568; WdT[f * 64 + o] = Wd[i]; }
  if (i < 9216) {
    int oc = i / 288, k = i % 288, ic = k / 9, kk = k % 9;
    w2T[kk * 1024 + ic * 32 + oc] = W2[i];
  }
  if (i < 288) { int oc = i / 9, k = i % 9; w1T[k * 32 + oc] = W1[i]; }
}

// ---------------------------------------------------------------------------
// Stage 1: conv1(3x3 SAME, 1->32) + LIF + maxpool, lane-parallel over t.
// (unchanged from passing rounds 6-11)
// ---------------------------------------------------------------------------
__global__ __launch_bounds__(128) void k_stage1M(const unsigned* __restrict__ mIn,
                                                 const float* __restrict__ w1T,
                                                 unsigned* __restrict__ z1p) {
  __shared__ float xp[2][20 * 66];
  int lane = threadIdx.x & 63;
  int wid  = threadIdx.x >> 6;
  int gw   = blockIdx.x * 2 + wid;     // wave index
  int pA = 2 * gw, pB = 2 * gw + 1;    // pre-pool pixel = b*784 + y*28 + x
  int bA = pA / 784, rA = pA % 784, yA = rA / 28, xA = rA % 28;
  int bB = pB / 784, rB = pB % 784, yB = rB / 28, xB = rB % 28;
  int tl = lane & 31, hiB = lane >> 5;

  unsigned mA[9], mB[9];
  for (int ky = 0; ky < 3; ++ky) {
    for (int kx = 0; kx < 3; ++kx) {
      int k = ky * 3 + kx;
      int ya = yA - 1 + ky, xa = xA - 1 + kx;
      int yb = yB - 1 + ky, xb = xB - 1 + kx;
      mA[k] = (ya >= 0 && ya < 28 && xa >= 0 && xa < 28) ? mIn[bA * 784 + ya * 28 + xa] : 0u;
      mB[k] = (yb >= 0 && yb < 28 && xb >= 0 && xb < 28) ? mIn[bB * 784 + yb * 28 + xb] : 0u;
    }
  }

  float acc[32];
#pragma unroll
  for (int o = 0; o < 32; ++o) acc[o] = 0.0f;

  for (int k = 0; k < 9; ++k) {
    unsigned long long m64 = ((unsigned long long)mB[k] << 32) | (unsigned long long)mA[k];
    float bitf = (float)((m64 >> lane) & 1ull);
    const float* wrow = w1T + k * 32;
#pragma unroll
    for (int oc = 0; oc < 32; ++oc)
      acc[oc] = fmaf(wrow[oc], bitf, acc[oc]);
  }

  if (tl < 20) {
#pragma unroll
    for (int oc = 0; oc < 32; ++oc)
      xp[wid][tl * 66 + hiB * 32 + oc] = acc[oc];
  }
  __syncthreads();

  float v = 0.0f;
  int   r = 0;
  unsigned zm = 0u;
#pragma unroll
  for (int t = 0; t < 20; ++t) {
    float c = xp[wid][t * 66 + lane];
    v += c;
    bool z = (v > THRF) && (r == 0);
    if (z) { v -= THRF; r = 3; } else if (r > 0) --r;
    if (z) zm |= 1u << t;
  }
  int p = hiB ? pB : pA;
  int b = p / 784, rr = p % 784, y = rr / 28, x = rr % 28;
  atomicOr(&z1p[((b * 14 + (y >> 1)) * 14 + (x >> 1)) * 32 + tl], zm);
}

// ---------------------------------------------------------------------------
// Stage 2: conv2 + LIF + maxpool. Round-9 stage2E inner loop VERBATIM
// (best measured: VMEM broadcast weights + wide vector mask loads +
// readlane/cndmask extract; masks prefetched one cell ahead) + round-11's
// compact per-wave epilogue ([20][33] buffer, 3 wave-internal sub-passes,
// ZERO barriers) so LDS/block drops 31->10.5 KB and 8 blocks/CU fit.
// Accumulation per (neuron,t): ascending (ky,kx,ic), ic innermost —
// identical to all passing rounds; bit=0 terms add +0.0 (exact no-op).
// ---------------------------------------------------------------------------
__global__ __launch_bounds__(256) void k_stage2H(const unsigned* __restrict__ z1p,
                                                 const float* __restrict__ wT2,
                                                 const unsigned* __restrict__ zbuf,
                                                 unsigned* __restrict__ z2p) {
  __shared__ float xp[4][20 * 33];     // per-wave epilogue transpose (10.5 KB)
  int lane = threadIdx.x & 63;
  int wid  = threadIdx.x >> 6;
  int gw   = blockIdx.x * 4 + wid;     // wave index
  int q0 = 3 * gw;                     // pixels: b*196 + y*14 + x

  int bb[3], yy[3], xx[3];
  bool vq[3];
#pragma unroll
  for (int j = 0; j < 3; ++j) {
    int q = q0 + j;
    vq[j] = q < 25088;
    int qs = vq[j] ? q : 0;
    bb[j] = qs / 196; int rr = qs % 196; yy[j] = rr / 14; xx[j] = rr % 14;
  }

  int  li = lane & 31;
  bool lo = lane < 32;
  int  p  = lane / 20;                 // 0..3 (p==3 idle in epilogue)
  int  tl = lane - p * 20;

  float acc[32];
#pragma unroll
  for (int o = 0; o < 32; ++o) acc[o] = 0.0f;

  auto cptr = [&](int cell, const unsigned*& c0, const unsigned*& c1,
                  const unsigned*& c2) {
    int ky = cell / 3, kx = cell % 3;
    const unsigned* cp[3];
#pragma unroll
    for (int j = 0; j < 3; ++j) {
      int y = yy[j] - 1 + ky, x = xx[j] - 1 + kx;
      bool ok = vq[j] && y >= 0 && y < 14 && x >= 0 && x < 14;
      cp[j] = ok ? (z1p + ((bb[j] * 14 + y) * 14 + x) * 32) : zbuf;
    }
    c0 = cp[0]; c1 = cp[1]; c2 = cp[2];
  };

  const unsigned *c0, *c1, *c2;
  cptr(0, c0, c1, c2);
  unsigned va = (lo ? c0 : c1)[li];    // lanes 0-31: c0[li], 32-63: c1[li]
  unsigned vb = c2[li];

  for (int cell = 0; cell < 9; ++cell) {
    // prefetch next cell's masks
    unsigned va_n = 0u, vb_n = 0u;
    if (cell + 1 < 9) {
      const unsigned *n0, *n1, *n2;
      cptr(cell + 1, n0, n1, n2);
      va_n = (lo ? n0 : n1)[li];
      vb_n = n2[li];
    }
    const float* wc = wT2 + cell * 1024;
#pragma unroll 4
    for (int ic = 0; ic < 32; ++ic) {
      unsigned s0 = (unsigned)__builtin_amdgcn_readlane((int)va, ic);
      unsigned s1 = (unsigned)__builtin_amdgcn_readlane((int)va, 32 + ic);
      unsigned s2 = (unsigned)__builtin_amdgcn_readlane((int)vb, ic);
      unsigned mm = (p == 0) ? s0 : ((p == 1) ? s1 : s2);
      float bitf = (float)((mm >> tl) & 1u);
      const float* wrow = wc + ic * 32;
#pragma unroll
      for (int oc = 0; oc < 32; ++oc)
        acc[oc] = fmaf(wrow[oc], bitf, acc[oc]);
    }
    va = va_n; vb = vb_n;
  }

  // per-wave epilogue: 3 sub-passes (pixel j); wave-internal LDS ordering,
  // no barriers (per-wave buffer; all 64 lanes execute every sub-pass).
  float* xw = xp[wid];
#pragma unroll
  for (int j = 0; j < 3; ++j) {
    if (p == j) {
#pragma unroll
      for (int oc = 0; oc < 32; ++oc) xw[tl * 33 + oc] = acc[oc];
    }
    int oc = lane & 31;
    float v = 0.0f;
    int   r = 0;
    unsigned zm = 0u;
#pragma unroll
    for (int t = 0; t < 20; ++t) {
      float c = xw[t * 33 + oc];
      v += c;
      bool z = (v > THRF) && (r == 0);
      if (z) { v -= THRF; r = 3; } else if (r > 0) --r;
      if (z) zm |= 1u << t;
    }
    if (lane < 32 && vq[j])
      atomicOr(&z2p[bb[j] * 1568 + oc * 49 + (yy[j] >> 1) * 7 + (xx[j] >> 1)], zm);
  }
}

// ---------------------------------------------------------------------------
// Stage 3: dense currents + OUTPUT LIF fused (unchanged from rounds 9-11).
// 3 outputs/wave, 4 waves/block, A/B double-buffered mask+weight prefetch.
// ---------------------------------------------------------------------------
__global__ __launch_bounds__(256) void k_denseF(const unsigned* __restrict__ z2p,
                                                const float* __restrict__ WdT,
                                                float* __restrict__ out) {
  int lane = threadIdx.x & 63;
  int wid  = threadIdx.x >> 6;
  int gw   = blockIdx.x * 4 + wid;     // b*22 + og
  if (gw >= 128 * 22) return;
  int b  = gw / 22, og = gw % 22;
  int p  = lane / 20;                  // 0..3 (p==3 idle)
  int t  = lane - p * 20;
  int o  = og * 3 + p;
  bool live = (p < 3) && (o < 64);
  int osafe = live ? o : 63;
  const unsigned* zb = z2p + b * 1568;

  unsigned mA[16], mB[16];
  float    wA[16], wB[16];
#pragma unroll
  for (int u = 0; u < 16; ++u) { mA[u] = zb[u]; wA[u] = WdT[u * 64 + osafe]; }

  float acc = 0.0f;
  for (int f0 = 0; f0 < 1568; f0 += 32) {   // 1568 = 32*49
#pragma unroll
    for (int u = 0; u < 16; ++u) {
      int fn = f0 + 16 + u;
      mB[u] = zb[fn]; wB[u] = WdT[fn * 64 + osafe];
    }
#pragma unroll
    for (int u = 0; u < 16; ++u) {
      float bitf = (float)((mA[u] >> t) & 1u);
      acc = fmaf(wA[u], bitf, acc);
    }
    if (f0 + 32 < 1568) {
#pragma unroll
      for (int u = 0; u < 16; ++u) {
        int fn = f0 + 32 + u;
        mA[u] = zb[fn]; wA[u] = WdT[fn * 64 + osafe];
      }
    }
#pragma unroll
    for (int u = 0; u < 16; ++u) {
      float bitf = (float)((mB[u] >> t) & 1u);
      acc = fmaf(wB[u], bitf, acc);
    }
  }

  float v = 0.0f;
  int   r = 0;
  unsigned zm = 0u;
#pragma unroll
  for (int tt = 0; tt < 20; ++tt) {
    float c = __shfl(acc, p * 20 + tt, 64);  // p==3 lanes: garbage, discarded
    v += c;
    bool z = (v > THRF) && (r == 0);
    if (z) { v -= THRF; r = 3; } else if (r > 0) --r;
    if (z) zm |= 1u << tt;
  }
  if (live) out[(b * 20 + t) * 64 + o] = ((zm >> t) & 1u) ? 1.0f : 0.0f;
}

extern "C" void kernel_launch(void* const* d_in, const int* in_sizes, int n_in,
                              void* d_out, int out_size, void* d_ws, size_t ws_size,
                              hipStream_t stream) {
  const float* x  = (const float*)d_in[0];  // [128,1,28,28]
  const float* W1 = (const float*)d_in[1];  // [32,1,3,3]
  const float* W2 = (const float*)d_in[2];  // [32,32,3,3]
  const float* Wd = (const float*)d_in[3];  // [64,1568]
  float* out = (float*)d_out;               // [128,20,64]

  char* ws = (char*)d_ws;
  unsigned* mIn  = (unsigned*)ws;                      // 401408 B (dead after stage1)
  unsigned* z1p  = (unsigned*)(ws + 655360);           // 3211264 B (zeroed; atomicOr)
  unsigned* z2p  = (unsigned*)(ws + 3866624);          // 802816 B (zeroed; atomicOr)
  unsigned* zbuf = (unsigned*)(ws + 4669440);          // 128 B zeros
  float*    w1T  = (float*)(ws + 4669568);             // 1152 B
  float*    w2T  = (float*)(ws + 4670720);             // 36864 B
  float*    WdT  = (float*)(ws + 4707584);             // 401408 B

  k_pre<<<dim3(392), dim3(256), 0, stream>>>(x, W1, W2, Wd, mIn, w1T, w2T, WdT);
  hipMemsetAsync(ws + 655360, 0, 3211264 + 802816 + 128, stream);  // z1p+z2p+zbuf
  k_stage1M<<<dim3(25088), dim3(128), 0, stream>>>(mIn, w1T, z1p);
  k_stage2H<<<dim3(2091), dim3(256), 0, stream>>>(z1p, w2T, zbuf, z2p);
  k_denseF<<<dim3(704), dim3(256), 0, stream>>>(z2p, WdT, out);
}

// Round 13
// 285.488 us; speedup vs baseline: 1.1311x; 1.0072x over previous
//
#include <hip/hip_runtime.h>

#define THRF 0.05f

typedef float f32x2 __attribute__((ext_vector_type(2)));
typedef float f32x4 __attribute__((ext_vector_type(4)));

// ---------------------------------------------------------------------------
// Fused pre-pass: latency encode (one-hot mask per pixel) + weight transposes.
//  w1T[k*32+oc]          = W1[oc*9+k]
//  w2T[kk*1024+ic*32+oc] = W2[oc*288+ic*9+kk]
//  WdT[f*64+o]           = Wd[o*1568+f]
// ---------------------------------------------------------------------------
__global__ void k_pre(const float* __restrict__ x, const float* __restrict__ W1,
                      const float* __restrict__ W2, const float* __restrict__ Wd,
                      unsigned* __restrict__ mIn, float* __restrict__ w1T,
                      float* __restrict__ w2T, float* __restrict__ WdT) {
  int i = blockIdx.x * blockDim.x + threadIdx.x;
  if (i >= 100352) return;
  float xv = x[i];
  float st = fminf(19.0f * (1.0f - xv), 19.0f * 0.95f);
  int t = (int)rintf(st);
  t = t < 0 ? 0 : (t > 19 ? 19 : t);
  mIn[i] = (xv >= THRF) ? (1u << t) : 0u;
  { int o = i / 1568, f = i % 1568; WdT[f * 64 + o] = Wd[i]; }
  if (i < 9216) {
    int oc = i / 288, k = i % 288, ic = k / 9, kk = k % 9;
    w2T[kk * 1024 + ic * 32 + oc] = W2[i];
  }
  if (i < 288) { int oc = i / 9, k = i % 9; w1T[k * 32 + oc] = W1[i]; }
}

// ---------------------------------------------------------------------------
// Stage 1: conv1(3x3 SAME, 1->32) + LIF + maxpool, lane-parallel over t.
// (unchanged from passing rounds 6-12)
// ---------------------------------------------------------------------------
__global__ __launch_bounds__(128) void k_stage1M(const unsigned* __restrict__ mIn,
                                                 const float* __restrict__ w1T,
                                                 unsigned* __restrict__ z1p) {
  __shared__ float xp[2][20 * 66];
  int lane = threadIdx.x & 63;
  int wid  = threadIdx.x >> 6;
  int gw   = blockIdx.x * 2 + wid;     // wave index
  int pA = 2 * gw, pB = 2 * gw + 1;    // pre-pool pixel = b*784 + y*28 + x
  int bA = pA / 784, rA = pA % 784, yA = rA / 28, xA = rA % 28;
  int bB = pB / 784, rB = pB % 784, yB = rB / 28, xB = rB % 28;
  int tl = lane & 31, hiB = lane >> 5;

  unsigned mA[9], mB[9];
  for (int ky = 0; ky < 3; ++ky) {
    for (int kx = 0; kx < 3; ++kx) {
      int k = ky * 3 + kx;
      int ya = yA - 1 + ky, xa = xA - 1 + kx;
      int yb = yB - 1 + ky, xb = xB - 1 + kx;
      mA[k] = (ya >= 0 && ya < 28 && xa >= 0 && xa < 28) ? mIn[bA * 784 + ya * 28 + xa] : 0u;
      mB[k] = (yb >= 0 && yb < 28 && xb >= 0 && xb < 28) ? mIn[bB * 784 + yb * 28 + xb] : 0u;
    }
  }

  float acc[32];
#pragma unroll
  for (int o = 0; o < 32; ++o) acc[o] = 0.0f;

  for (int k = 0; k < 9; ++k) {
    unsigned long long m64 = ((unsigned long long)mB[k] << 32) | (unsigned long long)mA[k];
    float bitf = (float)((m64 >> lane) & 1ull);
    const float* wrow = w1T + k * 32;
#pragma unroll
    for (int oc = 0; oc < 32; ++oc)
      acc[oc] = fmaf(wrow[oc], bitf, acc[oc]);
  }

  if (tl < 20) {
#pragma unroll
    for (int oc = 0; oc < 32; ++oc)
      xp[wid][tl * 66 + hiB * 32 + oc] = acc[oc];
  }
  __syncthreads();

  float v = 0.0f;
  int   r = 0;
  unsigned zm = 0u;
#pragma unroll
  for (int t = 0; t < 20; ++t) {
    float c = xp[wid][t * 66 + lane];
    v += c;
    bool z = (v > THRF) && (r == 0);
    if (z) { v -= THRF; r = 3; } else if (r > 0) --r;
    if (z) zm |= 1u << t;
  }
  int p = hiB ? pB : pA;
  int b = p / 784, rr = p % 784, y = rr / 28, x = rr % 28;
  atomicOr(&z1p[((b * 14 + (y >> 1)) * 14 + (x >> 1)) * 32 + tl], zm);
}

// ---------------------------------------------------------------------------
// Stage 2: conv2 + LIF + maxpool — round-12 structure with PACKED-FP32 inner
// loop. acc = 16x float2 (oc pairs); per ic: 3 readlane -> SALU 64-bit pack
// B = s0|s1<<20|s2<<40 -> per-lane shr64+and+cvt -> 16 v_pk_fma_f32 (each
// serving oc and oc+1; the two chains stay independent, so per-(neuron,t)
// accumulation remains ascending (ky,kx,ic), ic innermost — bit-identical
// to all passing rounds; bit=0 adds +0.0 exactly). Weights via 8 dwordx4
// VMEM broadcast loads (proven best path, rounds 8-12).
// Epilogue: per-wave [20][33] buffer, 3 wave-internal sub-passes, no
// barriers; pool via deterministic atomicOr into pre-zeroed z2p.
// ---------------------------------------------------------------------------
__global__ __launch_bounds__(256) void k_stage2I(const unsigned* __restrict__ z1p,
                                                 const float* __restrict__ wT2,
                                                 const unsigned* __restrict__ zbuf,
                                                 unsigned* __restrict__ z2p) {
  __shared__ float xp[4][20 * 33];     // per-wave epilogue transpose (10.5 KB)
  int lane = threadIdx.x & 63;
  int wid  = threadIdx.x >> 6;
  int gw   = blockIdx.x * 4 + wid;     // wave index
  int q0 = 3 * gw;                     // pixels: b*196 + y*14 + x

  int bb[3], yy[3], xx[3];
  bool vq[3];
#pragma unroll
  for (int j = 0; j < 3; ++j) {
    int q = q0 + j;
    vq[j] = q < 25088;
    int qs = vq[j] ? q : 0;
    bb[j] = qs / 196; int rr = qs % 196; yy[j] = rr / 14; xx[j] = rr % 14;
  }

  int  li = lane & 31;
  bool lo = lane < 32;
  int  p  = lane / 20;                 // 0..3 (p==3 idle in epilogue)
  int  tl = lane - p * 20;

  f32x2 acc2[16];
#pragma unroll
  for (int o = 0; o < 16; ++o) acc2[o] = (f32x2){0.0f, 0.0f};

  auto cptr = [&](int cell, const unsigned*& c0, const unsigned*& c1,
                  const unsigned*& c2) {
    int ky = cell / 3, kx = cell % 3;
    const unsigned* cp[3];
#pragma unroll
    for (int j = 0; j < 3; ++j) {
      int y = yy[j] - 1 + ky, x = xx[j] - 1 + kx;
      bool ok = vq[j] && y >= 0 && y < 14 && x >= 0 && x < 14;
      cp[j] = ok ? (z1p + ((bb[j] * 14 + y) * 14 + x) * 32) : zbuf;
    }
    c0 = cp[0]; c1 = cp[1]; c2 = cp[2];
  };

  const unsigned *c0, *c1, *c2;
  cptr(0, c0, c1, c2);
  unsigned va = (lo ? c0 : c1)[li];    // lanes 0-31: c0[li], 32-63: c1[li]
  unsigned vb = c2[li];

  for (int cell = 0; cell < 9; ++cell) {
    // prefetch next cell's masks
    unsigned va_n = 0u, vb_n = 0u;
    if (cell + 1 < 9) {
      const unsigned *n0, *n1, *n2;
      cptr(cell + 1, n0, n1, n2);
      va_n = (lo ? n0 : n1)[li];
      vb_n = n2[li];
    }
    const float* wc = wT2 + cell * 1024;
#pragma unroll 4
    for (int ic = 0; ic < 32; ++ic) {
      unsigned s0 = (unsigned)__builtin_amdgcn_readlane((int)va, ic);
      unsigned s1 = (unsigned)__builtin_amdgcn_readlane((int)va, 32 + ic);
      unsigned s2 = (unsigned)__builtin_amdgcn_readlane((int)vb, ic);
      unsigned long long B = (unsigned long long)s0 |
                             ((unsigned long long)s1 << 20) |
                             ((unsigned long long)s2 << 40);
      float bitf = (float)((B >> lane) & 1ull);   // lane = p*20 + t; 60-63 -> 0
      f32x2 bit2 = {bitf, bitf};
      const f32x4* w4 = (const f32x4*)(wc + ic * 32);
#pragma unroll
      for (int j = 0; j < 8; ++j) {
        f32x4 w = w4[j];
        f32x2 wlo = {w.x, w.y};
        f32x2 whi = {w.z, w.w};
        acc2[2 * j]     = __builtin_elementwise_fma(wlo, bit2, acc2[2 * j]);
        acc2[2 * j + 1] = __builtin_elementwise_fma(whi, bit2, acc2[2 * j + 1]);
      }
    }
    va = va_n; vb = vb_n;
  }

  // per-wave epilogue: 3 sub-passes (pixel j); wave-internal LDS ordering,
  // no barriers (per-wave buffer; all 64 lanes execute every sub-pass).
  float* xw = xp[wid];
#pragma unroll
  for (int j = 0; j < 3; ++j) {
    if (p == j) {
#pragma unroll
      for (int jj = 0; jj < 16; ++jj) {
        xw[tl * 33 + 2 * jj]     = acc2[jj].x;
        xw[tl * 33 + 2 * jj + 1] = acc2[jj].y;
      }
    }
    int oc = lane & 31;
    float v = 0.0f;
    int   r = 0;
    unsigned zm = 0u;
#pragma unroll
    for (int t = 0; t < 20; ++t) {
      float c = xw[t * 33 + oc];
      v += c;
      bool z = (v > THRF) && (r == 0);
      if (z) { v -= THRF; r = 3; } else if (r > 0) --r;
      if (z) zm |= 1u << t;
    }
    if (lane < 32 && vq[j])
      atomicOr(&z2p[bb[j] * 1568 + oc * 49 + (yy[j] >> 1) * 7 + (xx[j] >> 1)], zm);
  }
}

// ---------------------------------------------------------------------------
// Stage 3: dense currents + OUTPUT LIF fused (unchanged from rounds 9-12).
// NOTE: packed FP32 deliberately NOT used here — the accumulation chain runs
// over f for a fixed o; pairing f's would split the chain (order change).
// ---------------------------------------------------------------------------
__global__ __launch_bounds__(256) void k_denseF(const unsigned* __restrict__ z2p,
                                                const float* __restrict__ WdT,
                                                float* __restrict__ out) {
  int lane = threadIdx.x & 63;
  int wid  = threadIdx.x >> 6;
  int gw   = blockIdx.x * 4 + wid;     // b*22 + og
  if (gw >= 128 * 22) return;
  int b  = gw / 22, og = gw % 22;
  int p  = lane / 20;                  // 0..3 (p==3 idle)
  int t  = lane - p * 20;
  int o  = og * 3 + p;
  bool live = (p < 3) && (o < 64);
  int osafe = live ? o : 63;
  const unsigned* zb = z2p + b * 1568;

  unsigned mA[16], mB[16];
  float    wA[16], wB[16];
#pragma unroll
  for (int u = 0; u < 16; ++u) { mA[u] = zb[u]; wA[u] = WdT[u * 64 + osafe]; }

  float acc = 0.0f;
  for (int f0 = 0; f0 < 1568; f0 += 32) {   // 1568 = 32*49
#pragma unroll
    for (int u = 0; u < 16; ++u) {
      int fn = f0 + 16 + u;
      mB[u] = zb[fn]; wB[u] = WdT[fn * 64 + osafe];
    }
#pragma unroll
    for (int u = 0; u < 16; ++u) {
      float bitf = (float)((mA[u] >> t) & 1u);
      acc = fmaf(wA[u], bitf, acc);
    }
    if (f0 + 32 < 1568) {
#pragma unroll
      for (int u = 0; u < 16; ++u) {
        int fn = f0 + 32 + u;
        mA[u] = zb[fn]; wA[u] = WdT[fn * 64 + osafe];
      }
    }
#pragma unroll
    for (int u = 0; u < 16; ++u) {
      float bitf = (float)((mB[u] >> t) & 1u);
      acc = fmaf(wB[u], bitf, acc);
    }
  }

  float v = 0.0f;
  int   r = 0;
  unsigned zm = 0u;
#pragma unroll
  for (int tt = 0; tt < 20; ++tt) {
    float c = __shfl(acc, p * 20 + tt, 64);  // p==3 lanes: garbage, discarded
    v += c;
    bool z = (v > THRF) && (r == 0);
    if (z) { v -= THRF; r = 3; } else if (r > 0) --r;
    if (z) zm |= 1u << tt;
  }
  if (live) out[(b * 20 + t) * 64 + o] = ((zm >> t) & 1u) ? 1.0f : 0.0f;
}

extern "C" void kernel_launch(void* const* d_in, const int* in_sizes, int n_in,
                              void* d_out, int out_size, void* d_ws, size_t ws_size,
                              hipStream_t stream) {
  const float* x  = (const float*)d_in[0];  // [128,1,28,28]
  const float* W1 = (const float*)d_in[1];  // [32,1,3,3]
  const float* W2 = (const float*)d_in[2];  // [32,32,3,3]
  const float* Wd = (const float*)d_in[3];  // [64,1568]
  float* out = (float*)d_out;               // [128,20,64]

  char* ws = (char*)d_ws;
  unsigned* mIn  = (unsigned*)ws;                      // 401408 B (dead after stage1)
  unsigned* z1p  = (unsigned*)(ws + 655360);           // 3211264 B (zeroed; atomicOr)
  unsigned* z2p  = (unsigned*)(ws + 3866624);          // 802816 B (zeroed; atomicOr)
  unsigned* zbuf = (unsigned*)(ws + 4669440);          // 128 B zeros
  float*    w1T  = (float*)(ws + 4669568);             // 1152 B
  float*    w2T  = (float*)(ws + 4670720);             // 36864 B
  float*    WdT  = (float*)(ws + 4707584);             // 401408 B

  k_pre<<<dim3(392), dim3(256), 0, stream>>>(x, W1, W2, Wd, mIn, w1T, w2T, WdT);
  hipMemsetAsync(ws + 655360, 0, 3211264 + 802816 + 128, stream);  // z1p+z2p+zbuf
  k_stage1M<<<dim3(25088), dim3(128), 0, stream>>>(mIn, w1T, z1p);
  k_stage2I<<<dim3(2091), dim3(256), 0, stream>>>(z1p, w2T, zbuf, z2p);
  k_denseF<<<dim3(704), dim3(256), 0, stream>>>(z2p, WdT, out);
}